// Round 3
// baseline (467.394 us; speedup 1.0000x reference)
//
#include <hip/hip_runtime.h>
#include <hip/hip_bf16.h>
#include <stdint.h>

// VQ: N=524288 rows, D=64, K=512 codes.
// out = [quantized (N*64 f32), vq_loss (1 f32)]
// loss = 1.1 * sum_rows(x_sq + (e_sq[best] - 2*dot[best])) / (N*D)
//
// Structure: NO LDS, NO barriers. bf16 codebook image (64 KB) + e_sq (2 KB)
// live in d_ws and stay L2-resident (shared by all blocks). Streaming W
// reads / out writes are nontemporal so they don't evict the image.

#define N_ROWS 524288
#define DIM    64
#define KC     512
#define BM     256            // rows per block (8 waves x 32 rows)
#define THREADS 512
#define GRID   (N_ROWS / BM)  // 2048

// d_ws layout:
//   [0, 2048)        e_sq f32[512]
//   [2048, 67584)    codebook bf16 row-major [512][64]
//   [67584, 67588)   loss accumulator f32 (zeroed by prep)
#define ESQ_OFF 0
#define CB_OFF  2048
#define ACC_OFF 67584

typedef __attribute__((ext_vector_type(8))) short short8;   // 8 bf16
typedef __attribute__((ext_vector_type(4))) float floatx4;  // clang vector: ok for nontemporal builtins

__device__ __forceinline__ short bf16s(float f) {
    __hip_bfloat16 h = __float2bfloat16(f);           // RNE; pairs fuse to v_cvt_pk
    return __builtin_bit_cast(short, h);
}

// ---------- prep: bf16 image + e_sq + zero the loss accumulator ----------
// grid 32 x 256; thread t of block b: row = b*16 + t/16, cols (t%16)*4 .. +4
__global__ void vq_prep(const float* __restrict__ cb, char* __restrict__ ws) {
    int t = threadIdx.x;
    int row = blockIdx.x * 16 + (t >> 4);
    int q4 = (t & 15) * 4;
    if (blockIdx.x == 0 && t == 0) *(float*)(ws + ACC_OFF) = 0.0f;
    floatx4 v = *(const floatx4*)(cb + row * 64 + q4);
    float p = v.x * v.x + v.y * v.y + v.z * v.z + v.w * v.w;
    p += __shfl_xor(p, 1); p += __shfl_xor(p, 2);
    p += __shfl_xor(p, 4); p += __shfl_xor(p, 8);
    if ((t & 15) == 0) ((float*)(ws + ESQ_OFF))[row] = p;
    ushort4 b;
    b.x = (unsigned short)bf16s(v.x); b.y = (unsigned short)bf16s(v.y);
    b.z = (unsigned short)bf16s(v.z); b.w = (unsigned short)bf16s(v.w);
    *(ushort4*)(ws + CB_OFF + row * 128 + q4 * 2) = b;
}

// ---------- main: one 256-row tile per block, barrier-free ----------
__global__ __launch_bounds__(THREADS, 4) void vq_main(
    const float* __restrict__ w, const float* __restrict__ cbf,
    float* __restrict__ out, const char* __restrict__ ws)
{
    const int tid  = threadIdx.x;
    const int wave = tid >> 6;
    const int lane = tid & 63;
    const int g    = lane >> 4;   // k-group within fragment
    const int lc   = lane & 15;   // A-row / B-col / D-col within fragment

    const float* esq = (const float*)(ws + ESQ_OFF);
    const char*  img = ws + CB_OFF;

    // ---- A fragments: wave rows rowbase + t*16 + {0..15} ----
    const int rowbase = blockIdx.x * BM + wave * 32;
    short8 afrag[2][2];
    float xsq[2];
    #pragma unroll
    for (int t = 0; t < 2; ++t) {
        int row = rowbase + t * 16 + lc;
        const float* wr = w + (size_t)row * 64 + g * 8;
        floatx4 f0 = __builtin_nontemporal_load((const floatx4*)(wr));
        floatx4 f1 = __builtin_nontemporal_load((const floatx4*)(wr + 4));
        floatx4 f2 = __builtin_nontemporal_load((const floatx4*)(wr + 32));
        floatx4 f3 = __builtin_nontemporal_load((const floatx4*)(wr + 36));
        float p = f0.x*f0.x + f0.y*f0.y + f0.z*f0.z + f0.w*f0.w
                + f1.x*f1.x + f1.y*f1.y + f1.z*f1.z + f1.w*f1.w
                + f2.x*f2.x + f2.y*f2.y + f2.z*f2.z + f2.w*f2.w
                + f3.x*f3.x + f3.y*f3.y + f3.z*f3.z + f3.w*f3.w;
        p += __shfl_xor(p, 16); p += __shfl_xor(p, 32);
        xsq[t] = p;
        short8 a0, a1;
        a0[0]=bf16s(f0.x); a0[1]=bf16s(f0.y); a0[2]=bf16s(f0.z); a0[3]=bf16s(f0.w);
        a0[4]=bf16s(f1.x); a0[5]=bf16s(f1.y); a0[6]=bf16s(f1.z); a0[7]=bf16s(f1.w);
        a1[0]=bf16s(f2.x); a1[1]=bf16s(f2.y); a1[2]=bf16s(f2.z); a1[3]=bf16s(f2.w);
        a1[4]=bf16s(f3.x); a1[5]=bf16s(f3.y); a1[6]=bf16s(f3.z); a1[7]=bf16s(f3.w);
        afrag[t][0] = a0; afrag[t][1] = a1;
    }

    // ---- K-loop over 32 col-blocks of 16 codes; B from global (L2-hot) ----
    float best[2][4]; int bidx[2][4];
    #pragma unroll
    for (int t = 0; t < 2; ++t)
        #pragma unroll
        for (int r = 0; r < 4; ++r) { best[t][r] = 3.0e38f; bidx[t][r] = 0; }

    #pragma unroll 8
    for (int c = 0; c < 32; ++c) {
        const int col = c * 16 + lc;
        float  es = esq[col];
        const char* brow = img + (size_t)col * 128 + g * 16;
        short8 b0 = *(const short8*)(brow);        // k = 0..31 slice
        short8 b1 = *(const short8*)(brow + 64);   // k = 32..63 slice
        #pragma unroll
        for (int t = 0; t < 2; ++t) {
            floatx4 acc = {0.f, 0.f, 0.f, 0.f};
            acc = __builtin_amdgcn_mfma_f32_16x16x32_bf16(afrag[t][0], b0, acc, 0, 0, 0);
            acc = __builtin_amdgcn_mfma_f32_16x16x32_bf16(afrag[t][1], b1, acc, 0, 0, 0);
            #pragma unroll
            for (int r = 0; r < 4; ++r) {
                float sc = fmaf(-2.0f, acc[r], es);   // e_sq - 2*dot
                if (sc < best[t][r]) { best[t][r] = sc; bidx[t][r] = col; }
            }
        }
    }

    // ---- argmin across the 16 lanes (col classes) of each k-group ----
    #pragma unroll
    for (int t = 0; t < 2; ++t)
        #pragma unroll
        for (int r = 0; r < 4; ++r) {
            float b = best[t][r]; int i = bidx[t][r];
            #pragma unroll
            for (int d = 1; d < 16; d <<= 1) {
                float ob = __shfl_xor(b, d);
                int   oi = __shfl_xor(i, d);
                if (ob < b || (ob == b && oi < i)) { b = ob; i = oi; }
            }
            best[t][r] = b; bidx[t][r] = i;
        }

    // ---- write quantized rows: D-row = g*4 + r, 16 lanes x float4 ----
    #pragma unroll
    for (int t = 0; t < 2; ++t)
        #pragma unroll
        for (int r = 0; r < 4; ++r) {
            int row = rowbase + t * 16 + g * 4 + r;
            int idx = bidx[t][r];
            floatx4 v = *(const floatx4*)(cbf + (size_t)idx * 64 + lc * 4);
            __builtin_nontemporal_store(v, (floatx4*)(out + (size_t)row * 64 + lc * 4));
        }

    // ---- loss partial: xsq counted 4x per row, best 16x -> weights ----
    float v = (xsq[0] + xsq[1]) * 0.25f
            + (best[0][0] + best[0][1] + best[0][2] + best[0][3]
             + best[1][0] + best[1][1] + best[1][2] + best[1][3]) * 0.0625f;
    #pragma unroll
    for (int d = 1; d < 64; d <<= 1) v += __shfl_xor(v, d);
    if (lane == 0) atomicAdd((float*)(ws + ACC_OFF), v);
}

// ---------- finalize: scale accumulator -> loss scalar ----------
__global__ void vq_finalize(const char* __restrict__ ws, float* __restrict__ out_loss) {
    if (threadIdx.x == 0) {
        float acc = *(const float*)(ws + ACC_OFF);
        *out_loss = acc * (1.1f / 33554432.0f);
    }
}

extern "C" void kernel_launch(void* const* d_in, const int* in_sizes, int n_in,
                              void* d_out, int out_size, void* d_ws, size_t ws_size,
                              hipStream_t stream) {
    const float* w  = (const float*)d_in[0];
    const float* cb = (const float*)d_in[1];
    float* out = (float*)d_out;
    char*  ws  = (char*)d_ws;

    vq_prep<<<32, 256, 0, stream>>>(cb, ws);
    vq_main<<<GRID, THREADS, 0, stream>>>(w, cb, out, ws);
    vq_finalize<<<1, 64, 0, stream>>>(ws, out + (size_t)N_ROWS * DIM);
}

// Round 5
// 268.137 us; speedup vs baseline: 1.7431x; 1.7431x over previous
//
#include <hip/hip_runtime.h>
#include <hip/hip_bf16.h>
#include <stdint.h>

// VQ: N=524288 rows, D=64, K=512 codes.
// out = [quantized (N*64 f32), vq_loss (1 f32)]
// loss = 1.1 * sum_rows(x_sq + (e_sq[best] - 2*dot[best])) / (N*D)
//
// Structure: bf16 codebook image staged ONCE per block into 64KB LDS
// (XOR-swizzled, conflict-free), amortized over 4 row-tiles per block
// (grid=512, 2 blocks/CU). e_sq (pre-biased +0.5) stays global (2KB, L1-hot).
// Argmin via monotone-uint key + v_min_u32. No same-address atomics: per-block
// partials + finalize reduce.

#define N_ROWS 524288
#define DIM    64
#define KC     512
#define TILE_ROWS 256          // 8 waves x 32 rows
#define THREADS 512
#define NBLOCKS 512
#define TPB     4              // tiles per block: 512*4 = 2048 tiles

// d_ws layout:
//   [0, 2048)        e_sq + 0.5f  f32[512]
//   [2048, 67584)    codebook bf16, XOR-swizzled [512][64]
//   [67584, 69632)   partials f32[512]
#define ESQ_OFF  0
#define CB_OFF   2048
#define PART_OFF 67584

typedef __attribute__((ext_vector_type(8))) short short8;   // 8 bf16
typedef __attribute__((ext_vector_type(4))) float floatx4;

typedef const __attribute__((address_space(1))) uint8_t* gptr_t;
typedef __attribute__((address_space(3))) uint8_t* lptr_t;

__device__ __forceinline__ short bf16s(float f) {
    __hip_bfloat16 h = __float2bfloat16(f);
    return __builtin_bit_cast(short, h);
}

// ---------- prep: swizzled bf16 image + biased e_sq + zero partials ----------
// grid 32 x 256; thread t of block b: row = b*16 + t/16, cols (t%16)*4 .. +4
__global__ void vq_prep(const float* __restrict__ cb, char* __restrict__ ws) {
    int t = threadIdx.x;
    int row = blockIdx.x * 16 + (t >> 4);
    int q4 = (t & 15) * 4;
    if (blockIdx.x < 2) ((float*)(ws + PART_OFF))[blockIdx.x * 256 + t] = 0.0f;
    floatx4 v = *(const floatx4*)(cb + row * 64 + q4);
    float p = v.x * v.x + v.y * v.y + v.z * v.z + v.w * v.w;
    p += __shfl_xor(p, 1); p += __shfl_xor(p, 2);
    p += __shfl_xor(p, 4); p += __shfl_xor(p, 8);
    if ((t & 15) == 0) ((float*)(ws + ESQ_OFF))[row] = p + 0.5f;   // pre-biased
    ushort4 b;
    b.x = (unsigned short)bf16s(v.x); b.y = (unsigned short)bf16s(v.y);
    b.z = (unsigned short)bf16s(v.z); b.w = (unsigned short)bf16s(v.w);
    // byte offset within row: (q4*2) ^ ((row&7)<<4)  (16B-slot XOR swizzle)
    *(ushort4*)(ws + CB_OFF + row * 128 + ((q4 * 2) ^ ((row & 7) << 4))) = b;
}

// ---------- main ----------
__global__ __launch_bounds__(THREADS, 4) void vq_main(
    const float* __restrict__ w, const float* __restrict__ cbf,
    float* __restrict__ out, const char* __restrict__ ws,
    float* __restrict__ partials)
{
    __shared__ __align__(16) unsigned char simg[65536];
    const int tid  = threadIdx.x;
    const int wave = tid >> 6;
    const int lane = tid & 63;
    const int g    = lane >> 4;   // k-group within fragment
    const int lc   = lane & 15;   // A-load row / B-col / D-col

    const float* esq5 = (const float*)(ws + ESQ_OFF);
    const char*  img  = ws + CB_OFF;

    // ---- stage 64KB image once (linear: image pre-swizzled in ws) ----
    {
        #pragma unroll
        for (int i = 0; i < 8; ++i) {
            int off = i * 8192 + tid * 16;
            __builtin_amdgcn_global_load_lds((gptr_t)(img + off),
                                             (lptr_t)(simg + off), 16, 0, 0);
        }
    }
    __syncthreads();   // image valid; only barrier in the kernel

    float lossacc = 0.0f;

    for (int tt = 0; tt < TPB; ++tt) {
        const int tile = blockIdx.x * TPB + tt;
        const int rowbase = tile * TILE_ROWS + wave * 32;

        // ---- A fragments: rows rowbase + t*16 + lc ----
        short8 afrag[2][2];
        float xsq[2];
        #pragma unroll
        for (int t = 0; t < 2; ++t) {
            int row = rowbase + t * 16 + lc;
            const float* wr = w + (size_t)row * 64 + g * 8;
            floatx4 f0 = __builtin_nontemporal_load((const floatx4*)(wr));
            floatx4 f1 = __builtin_nontemporal_load((const floatx4*)(wr + 4));
            floatx4 f2 = __builtin_nontemporal_load((const floatx4*)(wr + 32));
            floatx4 f3 = __builtin_nontemporal_load((const floatx4*)(wr + 36));
            float p = f0.x*f0.x + f0.y*f0.y + f0.z*f0.z + f0.w*f0.w
                    + f1.x*f1.x + f1.y*f1.y + f1.z*f1.z + f1.w*f1.w
                    + f2.x*f2.x + f2.y*f2.y + f2.z*f2.z + f2.w*f2.w
                    + f3.x*f3.x + f3.y*f3.y + f3.z*f3.z + f3.w*f3.w;
            p += __shfl_xor(p, 16); p += __shfl_xor(p, 32);
            xsq[t] = p;
            short8 a0, a1;
            a0[0]=bf16s(f0.x); a0[1]=bf16s(f0.y); a0[2]=bf16s(f0.z); a0[3]=bf16s(f0.w);
            a0[4]=bf16s(f1.x); a0[5]=bf16s(f1.y); a0[6]=bf16s(f1.z); a0[7]=bf16s(f1.w);
            a1[0]=bf16s(f2.x); a1[1]=bf16s(f2.y); a1[2]=bf16s(f2.z); a1[3]=bf16s(f2.w);
            a1[4]=bf16s(f3.x); a1[5]=bf16s(f3.y); a1[6]=bf16s(f3.z); a1[7]=bf16s(f3.w);
            afrag[t][0] = a0; afrag[t][1] = a1;
        }

        // ---- K-loop: LDS B-reads (swizzled), key = (bits(score)&~511)|col ----
        unsigned int key[2][4];
        #pragma unroll
        for (int t = 0; t < 2; ++t)
            #pragma unroll
            for (int r = 0; r < 4; ++r) key[t][r] = 0xFFFFFFFFu;

        #pragma unroll 8
        for (int c = 0; c < 32; ++c) {
            const int col = c * 16 + lc;
            const float es5 = esq5[col];
            const int roff = col * 128;
            const int sw   = (col & 7) << 4;
            short8 b0 = *(const short8*)(simg + roff + ((g * 16) ^ sw));
            short8 b1 = *(const short8*)(simg + roff + ((64 + g * 16) ^ sw));
            floatx4 acc0 = {0.f,0.f,0.f,0.f}, acc1 = {0.f,0.f,0.f,0.f};
            acc0 = __builtin_amdgcn_mfma_f32_16x16x32_bf16(afrag[0][0], b0, acc0, 0, 0, 0);
            acc0 = __builtin_amdgcn_mfma_f32_16x16x32_bf16(afrag[0][1], b1, acc0, 0, 0, 0);
            acc1 = __builtin_amdgcn_mfma_f32_16x16x32_bf16(afrag[1][0], b0, acc1, 0, 0, 0);
            acc1 = __builtin_amdgcn_mfma_f32_16x16x32_bf16(afrag[1][1], b1, acc1, 0, 0, 0);
            #pragma unroll
            for (int r = 0; r < 4; ++r) {
                float s0 = fmaf(-2.0f, acc0[r], es5);   // strictly positive
                float s1 = fmaf(-2.0f, acc1[r], es5);
                unsigned int k0 = (__float_as_uint(s0) & 0xFFFFFE00u) | (unsigned)col;
                unsigned int k1 = (__float_as_uint(s1) & 0xFFFFFE00u) | (unsigned)col;
                key[0][r] = min(key[0][r], k0);
                key[1][r] = min(key[1][r], k1);
            }
        }

        // ---- reduce keys across the 16 lanes (col classes) of each g-group ----
        float kfsum = 0.0f;
        #pragma unroll
        for (int t = 0; t < 2; ++t)
            #pragma unroll
            for (int r = 0; r < 4; ++r) {
                unsigned int k = key[t][r];
                #pragma unroll
                for (int d = 1; d < 16; d <<= 1)
                    k = min(k, (unsigned int)__shfl_xor((int)k, d));
                key[t][r] = k;
                kfsum += __uint_as_float(k & 0xFFFFFE00u);
            }

        // ---- write quantized rows: D-row = g*4 + r ----
        #pragma unroll
        for (int t = 0; t < 2; ++t)
            #pragma unroll
            for (int r = 0; r < 4; ++r) {
                int row = rowbase + t * 16 + g * 4 + r;
                int idx = (int)(key[t][r] & 511u);
                floatx4 v = *(const floatx4*)(cbf + (size_t)idx * 64 + lc * 4);
                __builtin_nontemporal_store(v, (floatx4*)(out + (size_t)row * 64 + lc * 4));
            }

        // ---- loss: rows via xsq counted 4x, via keys counted 16x ----
        lossacc += (xsq[0] + xsq[1]) * 0.25f + (kfsum - 4.0f) * 0.0625f;
    }

    // single wave-reduce + one atomic per wave to a per-block slot
    #pragma unroll
    for (int d = 1; d < 64; d <<= 1) lossacc += __shfl_xor(lossacc, d);
    if (lane == 0) atomicAdd(&partials[blockIdx.x], lossacc);
}

// ---------- finalize: reduce 512 partials -> loss scalar ----------
__global__ void vq_finalize(const float* __restrict__ partials,
                            float* __restrict__ out_loss) {
    int tid = threadIdx.x;
    double s = (double)partials[tid] + (double)partials[tid + 256];
    #pragma unroll
    for (int d = 1; d < 64; d <<= 1) s += __shfl_xor(s, d);
    __shared__ double sd[4];
    if ((tid & 63) == 0) sd[tid >> 6] = s;
    __syncthreads();
    if (tid == 0) {
        double tot = sd[0] + sd[1] + sd[2] + sd[3];
        *out_loss = (float)(tot * (1.1 / 33554432.0));
    }
}

extern "C" void kernel_launch(void* const* d_in, const int* in_sizes, int n_in,
                              void* d_out, int out_size, void* d_ws, size_t ws_size,
                              hipStream_t stream) {
    const float* w  = (const float*)d_in[0];
    const float* cb = (const float*)d_in[1];
    float* out = (float*)d_out;
    char*  ws  = (char*)d_ws;
    float* partials = (float*)(ws + PART_OFF);

    vq_prep<<<32, 256, 0, stream>>>(cb, ws);
    vq_main<<<NBLOCKS, THREADS, 0, stream>>>(w, cb, out, ws, partials);
    vq_finalize<<<1, 256, 0, stream>>>(partials, out + (size_t)N_ROWS * DIM);
}